// Round 11
// baseline (56.130 us; speedup 1.0000x reference)
//
#include <hip/hip_runtime.h>

// Problem constants (match reference)
#define KK    5
#define PADV  2
#define NB    4
#define NC    32
#define NH    192
#define NW    192
#define NHO   96
#define NWO   96
#define NPX   (NHO * NWO)        // 9216
#define NPLANE (NB * NC * NPX)   // 1,179,648
#define EPSF  1e-20f

__device__ __forceinline__ float softplusf(float x) {
    return fmaxf(x, 0.f) + log1pf(expf(-fabsf(x)));
}
// post-argmax fast ops (1 ulp, smoothness-safe)
__device__ __forceinline__ float frcp(float x) { return __builtin_amdgcn_rcpf(x); }
__device__ __forceinline__ float fsqrt(float x) { return __builtin_amdgcn_sqrtf(x); }

// =====================================================================
// k1: per-(b, c, 8-row strip). Full-width 96x8 output tile, 768 threads.
//   Loads issued first (latency hidden under weight prep), LDS staging
//   as float4 quartets {pm, pv, cs, cs*s}, parity-split.
//   Phase B: 1 px/thread, 25 taps via 5 ds_read_b128/row with explicit
//   2-row register pipeline; companion trackers + sqrt recovery.
//   Writes {A,B,S,C} as one float4 per px.
// =====================================================================
#define TROWS 19
#define NJ    98     // column pairs (parity index 0..97)
#define PLD4  100    // padded leading dim (float4 elements)
#define K1T   768
#define ITEMS (TROWS * NJ)   // 1862

__global__ __launch_bounds__(K1T, 6) void k1(
    const float* __restrict__ dg,
    const float* __restrict__ cdg,
    const float* __restrict__ sg,
    const float* __restrict__ csg,
    const float* __restrict__ wsfdg,
    const float* __restrict__ spwg,
    float4* __restrict__ ws4)
{
    __shared__ float4 st_e[TROWS][PLD4];   // {pm, pv, cs, cs*s} even cols
    __shared__ float4 st_o[TROWS][PLD4];   // {pm, pv, cs, cs*s} odd cols
    __shared__ float sw_row[25];
    __shared__ float red[12];
    __shared__ float scal[2];   // sumsw, wsfd

    const int t  = threadIdx.x;
    const int bx = blockIdx.x;   // y-strip 0..11
    const int c  = blockIdx.y;
    const int b  = blockIdx.z;

    // ---- phase A-issue: compute item indices, fire all global loads ----
    const int gy0 = 16 * bx - 2;                   // top input row of patch
    const size_t base = ((size_t)(b * NC) + c) * (NH * NW);

    float2 Ld[3], Lcd[3], Ls[3], Lcs[3];
    int   rr_[3], jj_[3];
    bool  okv[3], act[3];
#pragma unroll
    for (int k = 0; k < 3; k++) {
        const int it = t + k * K1T;
        act[k] = (it < ITEMS);
        const int r = act[k] ? (it / NJ) : 0;
        const int j = act[k] ? (it - r * NJ) : 0;
        rr_[k] = r; jj_[k] = j;
        const int gy = gy0 + r;
        const bool ok = act[k] && ((unsigned)gy < NH) && (j >= 1) && (j <= 96);
        okv[k] = ok;
        float2 z = make_float2(0.f, 0.f);
        Ld[k] = z; Lcd[k] = z; Ls[k] = z; Lcs[k] = z;
        if (ok) {
            const size_t idx = base + (size_t)gy * NW + (2 * j - 2);  // 8B aligned
            Ld[k]  = *(const float2*)(dg  + idx);
            Lcd[k] = *(const float2*)(cdg + idx);
            Ls[k]  = *(const float2*)(sg  + idx);
            Lcs[k] = *(const float2*)(csg + idx);
        }
    }

    // ---- phase 0: weights (overlaps with loads in flight) ----
    float part = 0.f;
    for (int i = t; i < NC * 25; i += K1T) {
        float v = softplusf(spwg[i]);
        part += v;
        int cr = i - c * 25;
        if (cr >= 0 && cr < 25) sw_row[cr] = v;
    }
#pragma unroll
    for (int m = 32; m >= 1; m >>= 1) part += __shfl_xor(part, m, 64);
    if ((t & 63) == 0) red[t >> 6] = part;

    // ---- phase A-consume: derive + stage quartets ----
#pragma unroll
    for (int k = 0; k < 3; k++) {
        if (act[k]) {
            float pme, pve, pmo, pvo;
            if (okv[k]) {
                pme = Ld[k].x * Lcd[k].x;            // IEEE f32, matches np
                pve = Lcd[k].x / (Ld[k].x + EPSF);   // IEEE f32 div (argmax-critical)
                pmo = Ld[k].y * Lcd[k].y;
                pvo = Lcd[k].y / (Ld[k].y + EPSF);
            } else {
                pme = -INFINITY; pve = -INFINITY; pmo = -INFINITY; pvo = -INFINITY;
            }
            const int r = rr_[k], j = jj_[k];
            st_e[r][j] = make_float4(pme, pve, Lcs[k].x, Lcs[k].x * Ls[k].x);
            st_o[r][j] = make_float4(pmo, pvo, Lcs[k].y, Lcs[k].y * Ls[k].y);
        }
    }
    __syncthreads();
    if (t == 0) {
        float acc = 0.f;
#pragma unroll
        for (int i = 0; i < 12; i++) acc += red[i];
        scal[0] = acc;
        scal[1] = 1.f / (1.f + expf(-wsfdg[0]));
    }
    __syncthreads();

    // ---- phase B: one output px per thread, 2-row register pipeline ----
    const int oyl = t / 96;          // 0..7
    const int ox  = t - oyl * 96;    // 0..95
    const int r0  = oyl * 2;

    float bm = -INFINITY, bv = -INFINITY;
    float pvm = 0.f, pmn = 0.f;      // companions: pv@argmax(pm), pm@argmax(pv)
    float nom = 0.f, den = 0.f;

    // preload row r0
    float4 cE0 = st_e[r0][ox];
    float4 cO0 = st_o[r0][ox];
    float4 cE1 = st_e[r0][ox + 1];
    float4 cO1 = st_o[r0][ox + 1];
    float4 cE2 = st_e[r0][ox + 2];

#pragma unroll
    for (int dy = 0; dy < 5; dy++) {
        float4 nE0, nO0, nE1, nO1, nE2;
        if (dy < 4) {                      // prefetch next row (hides DS latency)
            const int rn = r0 + dy + 1;
            nE0 = st_e[rn][ox];
            nO0 = st_o[rn][ox];
            nE1 = st_e[rn][ox + 1];
            nO1 = st_o[rn][ox + 1];
            nE2 = st_e[rn][ox + 2];
        }
        const float w0 = sw_row[dy * 5 + 0];
        const float w1 = sw_row[dy * 5 + 1];
        const float w2 = sw_row[dy * 5 + 2];
        const float w3 = sw_row[dy * 5 + 3];
        const float w4 = sw_row[dy * 5 + 4];

        // taps in exact j order: dx = 0,1,2,3,4; strict > = first-max wins
        if (cE0.x > bm) { bm = cE0.x; pvm = cE0.y; }
        if (cE0.y > bv) { bv = cE0.y; pmn = cE0.x; }
        if (cO0.x > bm) { bm = cO0.x; pvm = cO0.y; }
        if (cO0.y > bv) { bv = cO0.y; pmn = cO0.x; }
        if (cE1.x > bm) { bm = cE1.x; pvm = cE1.y; }
        if (cE1.y > bv) { bv = cE1.y; pmn = cE1.x; }
        if (cO1.x > bm) { bm = cO1.x; pvm = cO1.y; }
        if (cO1.y > bv) { bv = cO1.y; pmn = cO1.x; }
        if (cE2.x > bm) { bm = cE2.x; pvm = cE2.y; }
        if (cE2.y > bv) { bv = cE2.y; pmn = cE2.x; }

        nom += w0 * cE0.w; den += w0 * cE0.z;
        nom += w1 * cO0.w; den += w1 * cO0.z;
        nom += w2 * cE1.w; den += w2 * cE1.z;
        nom += w3 * cO1.w; den += w3 * cO1.z;
        nom += w4 * cE2.w; den += w4 * cE2.z;

        if (dy < 4) { cE0 = nE0; cO0 = nO0; cE1 = nE1; cO1 = nO1; cE2 = nE2; }
    }

    // recover winner values algebraically (post-argmax: fast 1-ulp ops safe)
    //   bm = d_M*cd_M, pvm = cd_M/d_M ; bv = cd_N/d_N, pmn = d_N*cd_N
    const float t1 = pmn * pvm;
    const float t2 = bv * bm;
    const float mdm = fabsf(fsqrt(t1 * frcp(t2)));
    const float cfd = fsqrt(t1 * t2);

    const float sumsw = scal[0];
    const float wsfd  = scal[1];
    const float sfd  = (1.f - wsfd) * mdm + wsfd * mdm * mdm;
    const float ssp  = nom * frcp(den + EPSF);
    const float cssp = den * frcp(sumsw + EPSF);

    const int opx = (8 * bx + oyl) * NWO + ox;
    const size_t oidx = ((size_t)(b * NC) + c) * NPX + opx;
    ws4[oidx] = make_float4(cssp * ssp, cssp, sfd, cfd);   // {A,B,S,C}
}

// =====================================================================
// k2: channel mix + final combine. Thread = (o, 4-px quad); float4 LDS
// reads (pad 36 keeps rows 16B-aligned) + dwordx4 stores.
// =====================================================================
#define K2PX 32
#define K2PAD 36

__global__ __launch_bounds__(256, 8) void k2(
    const float4* __restrict__ ws4,
    const float* __restrict__ wpropg,
    const float* __restrict__ chwg,
    const float* __restrict__ biasg,
    float* __restrict__ out)
{
    __shared__ float cw_s[NC * NC];
    __shared__ float wp_s[NC];
    __shared__ float bias_s[NC];
    __shared__ float A_s[NC][K2PAD];
    __shared__ float B_s[NC][K2PAD];
    __shared__ float S_s[NC][K2PAD];
    __shared__ float C_s[NC][K2PAD];
    __shared__ float red[4];
    __shared__ float scal[1];

    const int t   = threadIdx.x;
    const int b   = blockIdx.y;
    const int px0 = blockIdx.x * K2PX;
    const int q   = t & 7;               // px quad 0..7 (4 px each)
    const int o   = t >> 3;              // 0..31

    float part = 0.f;
    for (int i = t; i < NC * NC; i += 256) {
        float v = softplusf(chwg[i]); cw_s[i] = v; part += v;
    }
    if (t < NC) { wp_s[t] = softplusf(wpropg[t]); bias_s[t] = biasg[t]; }
#pragma unroll
    for (int m = 32; m >= 1; m >>= 1) part += __shfl_xor(part, m, 64);
    if ((t & 63) == 0) red[t >> 6] = part;

    // stage quartets for this px tile (32 i x 32 px)
    const size_t bb = (size_t)b * NC * NPX;
#pragma unroll
    for (int idx = 0; idx < NC * K2PX; idx += 256) {
        const int i  = (idx + t) >> 5;
        const int pp = (idx + t) & (K2PX - 1);
        const float4 qv = ws4[bb + (size_t)i * NPX + px0 + pp];
        A_s[i][pp] = qv.x;
        B_s[i][pp] = qv.y;
        S_s[i][pp] = qv.z;
        C_s[i][pp] = qv.w;
    }
    __syncthreads();
    if (t == 0) scal[0] = red[0] + red[1] + red[2] + red[3];
    __syncthreads();

    const float sumcw = scal[0];

    float4 nom4 = make_float4(0.f, 0.f, 0.f, 0.f);
    float4 den4 = make_float4(0.f, 0.f, 0.f, 0.f);
#pragma unroll
    for (int i = 0; i < NC; i++) {
        const float4 a4 = *(const float4*)&A_s[i][4 * q];
        const float4 b4 = *(const float4*)&B_s[i][4 * q];
        const float w = cw_s[o * NC + i];
        nom4.x += w * a4.x; nom4.y += w * a4.y; nom4.z += w * a4.z; nom4.w += w * a4.w;
        den4.x += w * b4.x; den4.y += w * b4.y; den4.z += w * b4.z; den4.w += w * b4.w;
    }

    const float4 sfd4 = *(const float4*)&S_s[o][4 * q];
    const float4 cfd4 = *(const float4*)&C_s[o][4 * q];
    const float wp   = wp_s[o];
    const float bias = bias_s[o];
    const float csn  = frcp(sumcw + EPSF);

    float so[4], co[4];
#pragma unroll
    for (int k = 0; k < 4; k++) {
        const float nm  = (k == 0) ? nom4.x : (k == 1) ? nom4.y : (k == 2) ? nom4.z : nom4.w;
        const float dn  = (k == 0) ? den4.x : (k == 1) ? den4.y : (k == 2) ? den4.z : den4.w;
        const float sfd = (k == 0) ? sfd4.x : (k == 1) ? sfd4.y : (k == 2) ? sfd4.z : sfd4.w;
        const float cfd = (k == 0) ? cfd4.x : (k == 1) ? cfd4.y : (k == 2) ? cfd4.z : cfd4.w;

        const float smix  = nm * frcp(dn + EPSF);
        const float csmix = dn * csn;
        const float a = wp * csmix;

        float sout = (a * smix + cfd * sfd) * frcp(a + cfd + EPSF);
        const float csout = (a + cfd) * frcp(wp + 1.f);

        sout += bias;
        sout = frcp(1.f + __expf(-(sout * 2.f - 1.f))) * 0.5f + 0.5f;

        so[k] = sout;
        co[k] = csout * 0.25f;
    }

    const size_t oidx = bb + (size_t)o * NPX + px0 + 4 * q;
    *(float4*)&out[oidx]                     = make_float4(so[0], so[1], so[2], so[3]);
    *(float4*)&out[(size_t)NPLANE + oidx]    = make_float4(co[0], co[1], co[2], co[3]);
}

// =====================================================================
// Fallback: round-4 fused kernel (used if ws_size is too small)
// =====================================================================
#define TW    8
#define TH    4
#define TPP   33

__global__ __launch_bounds__(256, 4) void fused_kernel(
    const float* __restrict__ dg,
    const float* __restrict__ cdg,
    const float* __restrict__ sg,
    const float* __restrict__ csg,
    const float* __restrict__ wsfdg,
    const float* __restrict__ wpropg,
    const float* __restrict__ spwg,
    const float* __restrict__ chwg,
    const float* __restrict__ biasg,
    float* __restrict__ out)
{
    __shared__ float sw_s[NC * 25];
    __shared__ float cw_s[NC * NC];
    __shared__ float wp_s[NC];
    __shared__ float bias_s[NC];
    __shared__ float A_s[NC][TPP];
    __shared__ float B_s[NC][TPP];
    __shared__ float S_s[NC][TPP];
    __shared__ float C_s[NC][TPP];
    __shared__ float red[8];
    __shared__ float scal[3];

    const int t = threadIdx.x;
    const int b = blockIdx.z;
    const int tile_x = blockIdx.x * TW;
    const int tile_y = blockIdx.y * TH;

    float p_sw = 0.f, p_cw = 0.f;
    for (int i = t; i < NC * 25; i += 256) { float v = softplusf(spwg[i]); sw_s[i] = v; p_sw += v; }
    for (int i = t; i < NC * NC; i += 256) { float v = softplusf(chwg[i]); cw_s[i] = v; p_cw += v; }
    if (t < NC) { wp_s[t] = softplusf(wpropg[t]); bias_s[t] = biasg[t]; }
#pragma unroll
    for (int m = 32; m >= 1; m >>= 1) {
        p_sw += __shfl_xor(p_sw, m, 64);
        p_cw += __shfl_xor(p_cw, m, 64);
    }
    if ((t & 63) == 0) { red[(t >> 6) * 2] = p_sw; red[(t >> 6) * 2 + 1] = p_cw; }
    __syncthreads();
    if (t == 0) {
        scal[0] = red[0] + red[2] + red[4] + red[6];
        scal[1] = red[1] + red[3] + red[5] + red[7];
        scal[2] = 1.f / (1.f + expf(-wsfdg[0]));
    }
    __syncthreads();

    const float sumsw = scal[0];
    const float sumcw = scal[1];
    const float wsfd  = scal[2];

    const int c  = t >> 3;
    const int tr = (t >> 2) & 1;
    const int q  = t & 3;
    const int oy0 = tile_y + tr * 2;
    const int ox0 = tile_x + q * 2;
    const int cb = ox0 * 2 - 2;
    const int rb = oy0 * 2 - 2;
    const size_t base = ((size_t)(b * NC) + c) * NH * NW;
    const float* __restrict__ dp  = dg  + base;
    const float* __restrict__ cdp = cdg + base;
    const float* __restrict__ sp  = sg  + base;
    const float* __restrict__ csp = csg + base;

    bool slotok[4];
#pragma unroll
    for (int k = 0; k < 4; k++) slotok[k] = (cb + 2 * k >= 0) && (cb + 2 * k + 1 < NW);
    bool ciok[7];
#pragma unroll
    for (int ci = 0; ci < 7; ci++) ciok[ci] = ((unsigned)(cb + ci) < NW);

    float bm[2][2], dM[2][2], cM[2][2];
    float bn[2][2], dN[2][2], cN[2][2];
    float nom[2][2], den[2][2];
#pragma unroll
    for (int r = 0; r < 2; r++)
#pragma unroll
        for (int q2 = 0; q2 < 2; q2++) {
            bm[r][q2] = -INFINITY; bn[r][q2] = -INFINITY;
            dM[r][q2] = 0.f; cM[r][q2] = 0.f; dN[r][q2] = 0.f; cN[r][q2] = 0.f;
            nom[r][q2] = 0.f; den[r][q2] = 0.f;
        }

#pragma unroll
    for (int rr = 0; rr < 7; rr++) {
        const int iy = rb + rr;
        if ((unsigned)iy < NH) {
            const int roff = iy * NW + cb;
            float dv[8], cdv[8], sv[8], csv[8];
#pragma unroll
            for (int k = 0; k < 4; k++) {
                float2 vD, vCD, vS, vCS;
                if (slotok[k]) {
                    vD  = *(const float2*)(dp  + roff + 2 * k);
                    vCD = *(const float2*)(cdp + roff + 2 * k);
                    vS  = *(const float2*)(sp  + roff + 2 * k);
                    vCS = *(const float2*)(csp + roff + 2 * k);
                } else {
                    vD = make_float2(0.f, 0.f); vCD = vD; vS = vD; vCS = vD;
                }
                dv[2*k] = vD.x;  dv[2*k+1] = vD.y;
                cdv[2*k] = vCD.x; cdv[2*k+1] = vCD.y;
                sv[2*k] = vS.x;  sv[2*k+1] = vS.y;
                csv[2*k] = vCS.x; csv[2*k+1] = vCS.y;
            }
            float pm[7], pv[7];
#pragma unroll
            for (int ci = 0; ci < 7; ci++) {
                pm[ci] = dv[ci] * cdv[ci];
                pv[ci] = cdv[ci] / (dv[ci] + EPSF);
            }
#pragma unroll
            for (int r = 0; r < 2; r++) {
                const int dy = rr - 2 * r;
                if (dy >= 0 && dy <= 4) {
#pragma unroll
                    for (int dx = 0; dx < 5; dx++) {
                        const float w = sw_s[c * 25 + dy * 5 + dx];
#pragma unroll
                        for (int q2 = 0; q2 < 2; q2++) {
                            const int ci = 2 * q2 + dx;
                            if (ciok[ci]) {
                                if (pm[ci] > bm[r][q2]) { bm[r][q2] = pm[ci]; dM[r][q2] = dv[ci]; cM[r][q2] = cdv[ci]; }
                                if (pv[ci] > bn[r][q2]) { bn[r][q2] = pv[ci]; dN[r][q2] = dv[ci]; cN[r][q2] = cdv[ci]; }
                                nom[r][q2] += w * (csv[ci] * sv[ci]);
                                den[r][q2] += w * csv[ci];
                            }
                        }
                    }
                }
            }
        }
    }

#pragma unroll
    for (int r = 0; r < 2; r++)
#pragma unroll
        for (int q2 = 0; q2 < 2; q2++) {
            const float mdm  = fabsf(dN[r][q2] / (dM[r][q2] + EPSF));
            const float sfd  = (1.f - wsfd) * mdm + wsfd * mdm * mdm;
            const float cfd  = cM[r][q2] * cN[r][q2];
            const float ssp  = nom[r][q2] / (den[r][q2] + EPSF);
            const float cssp = den[r][q2] / (sumsw + EPSF);
            const int p = (tr * 2 + r) * TW + (q * 2 + q2);
            A_s[c][p] = cssp * ssp;
            B_s[c][p] = cssp;
            S_s[c][p] = sfd;
            C_s[c][p] = cfd;
        }
    __syncthreads();

    const int p  = t & 31;
    const int o0 = t >> 5;
    const int py = p >> 3;
    const int pxx = p & 7;
    const int opx = (tile_y + py) * NWO + tile_x + pxx;

    float nom2[4], den2[4];
#pragma unroll
    for (int k = 0; k < 4; k++) { nom2[k] = 0.f; den2[k] = 0.f; }

#pragma unroll
    for (int i = 0; i < NC; i++) {
        const float a  = A_s[i][p];
        const float b2 = B_s[i][p];
#pragma unroll
        for (int k = 0; k < 4; k++) {
            const float w = cw_s[(o0 + 8 * k) * NC + i];
            nom2[k] += w * a;
            den2[k] += w * b2;
        }
    }

#pragma unroll
    for (int k = 0; k < 4; k++) {
        const int o = o0 + 8 * k;
        const float smix  = nom2[k] / (den2[k] + EPSF);
        const float csmix = den2[k] / (sumcw + EPSF);
        const float wp    = wp_s[o];
        const float sfd   = S_s[o][p];
        const float cfd   = C_s[o][p];

        float sout = (wp * csmix * smix + cfd * sfd) / (wp * csmix + cfd + EPSF);
        const float csout = (wp * csmix + cfd) / (wp + 1.f);

        sout += bias_s[o];
        sout = 1.f / (1.f + expf(-(sout * 2.f - 1.f))) * 0.5f + 0.5f;

        const int oidx = ((b * NC) + o) * NPX + opx;
        out[oidx]          = sout;
        out[NPLANE + oidx] = csout * 0.25f;
    }
}

extern "C" void kernel_launch(void* const* d_in, const int* in_sizes, int n_in,
                              void* d_out, int out_size, void* d_ws, size_t ws_size,
                              hipStream_t stream) {
    const float* d     = (const float*)d_in[0];
    const float* cd    = (const float*)d_in[1];
    const float* s     = (const float*)d_in[2];
    const float* cs    = (const float*)d_in[3];
    const float* wsfd  = (const float*)d_in[4];
    const float* wprop = (const float*)d_in[5];
    const float* spw   = (const float*)d_in[6];
    const float* chw   = (const float*)d_in[7];
    const float* bias  = (const float*)d_in[8];
    float* out = (float*)d_out;

    const size_t need = (size_t)4 * NPLANE * sizeof(float);   // 18.9 MB
    if (ws_size >= need) {
        float4* ws4 = (float4*)d_ws;
        k1<<<dim3(NHO / 8, NC, NB), K1T, 0, stream>>>(d, cd, s, cs, wsfd, spw, ws4);
        k2<<<dim3(NPX / K2PX, NB), 256, 0, stream>>>(ws4, wprop, chw, bias, out);
    } else {
        fused_kernel<<<dim3(NWO / TW, NHO / TH, NB), 256, 0, stream>>>(
            d, cd, s, cs, wsfd, wprop, spw, chw, bias, out);
    }
}

// Round 12
// 38.460 us; speedup vs baseline: 1.4594x; 1.4594x over previous
//
#include <hip/hip_runtime.h>

// Problem constants (match reference)
#define KK    5
#define PADV  2
#define NB    4
#define NC    32
#define NH    192
#define NW    192
#define NHO   96
#define NWO   96
#define NPX   (NHO * NWO)        // 9216
#define NPLANE (NB * NC * NPX)   // 1,179,648
#define EPSF  1e-20f

__device__ __forceinline__ float softplusf(float x) {
    return fmaxf(x, 0.f) + log1pf(expf(-fabsf(x)));
}
// post-argmax fast ops (1 ulp, smoothness-safe)
__device__ __forceinline__ float frcp(float x) { return __builtin_amdgcn_rcpf(x); }
__device__ __forceinline__ float fsqrt(float x) { return __builtin_amdgcn_sqrtf(x); }

// =====================================================================
// k1: per-(b, c, 8-row strip). Full-width 96x8 output tile, 768 threads.
//   (round-9 structure verbatim: no register pipeline -> no spills)
//   Loads issued first, LDS staging as float4 quartets {pm,pv,cs,cs*s},
//   parity-split. Phase B: 1 px/thread, 25 taps via 5 b128/row;
//   companion trackers + sqrt recovery; fast-math tail.
// =====================================================================
#define TROWS 19
#define NJ    98     // column pairs (parity index 0..97)
#define PLD4  100    // padded leading dim (float4 elements)
#define K1T   768
#define ITEMS (TROWS * NJ)   // 1862

__global__ __launch_bounds__(K1T, 6) void k1(
    const float* __restrict__ dg,
    const float* __restrict__ cdg,
    const float* __restrict__ sg,
    const float* __restrict__ csg,
    const float* __restrict__ wsfdg,
    const float* __restrict__ spwg,
    float4* __restrict__ ws4)
{
    __shared__ float4 st_e[TROWS][PLD4];   // {pm, pv, cs, cs*s} even cols
    __shared__ float4 st_o[TROWS][PLD4];   // {pm, pv, cs, cs*s} odd cols
    __shared__ float sw_row[25];
    __shared__ float red[12];
    __shared__ float scal[2];   // sumsw, wsfd

    const int t  = threadIdx.x;
    const int bx = blockIdx.x;   // y-strip 0..11
    const int c  = blockIdx.y;
    const int b  = blockIdx.z;

    // ---- phase A-issue: compute item indices, fire all global loads ----
    const int gy0 = 16 * bx - 2;                   // top input row of patch
    const size_t base = ((size_t)(b * NC) + c) * (NH * NW);

    float2 Ld[3], Lcd[3], Ls[3], Lcs[3];
    int   rr_[3], jj_[3];
    bool  okv[3], act[3];
#pragma unroll
    for (int k = 0; k < 3; k++) {
        const int it = t + k * K1T;
        act[k] = (it < ITEMS);
        const int r = act[k] ? (it / NJ) : 0;
        const int j = act[k] ? (it - r * NJ) : 0;
        rr_[k] = r; jj_[k] = j;
        const int gy = gy0 + r;
        const bool ok = act[k] && ((unsigned)gy < NH) && (j >= 1) && (j <= 96);
        okv[k] = ok;
        float2 z = make_float2(0.f, 0.f);
        Ld[k] = z; Lcd[k] = z; Ls[k] = z; Lcs[k] = z;
        if (ok) {
            const size_t idx = base + (size_t)gy * NW + (2 * j - 2);  // 8B aligned
            Ld[k]  = *(const float2*)(dg  + idx);
            Lcd[k] = *(const float2*)(cdg + idx);
            Ls[k]  = *(const float2*)(sg  + idx);
            Lcs[k] = *(const float2*)(csg + idx);
        }
    }

    // ---- phase 0: weights (overlaps with loads in flight) ----
    float part = 0.f;
    for (int i = t; i < NC * 25; i += K1T) {
        float v = softplusf(spwg[i]);
        part += v;
        int cr = i - c * 25;
        if (cr >= 0 && cr < 25) sw_row[cr] = v;
    }
#pragma unroll
    for (int m = 32; m >= 1; m >>= 1) part += __shfl_xor(part, m, 64);
    if ((t & 63) == 0) red[t >> 6] = part;

    // ---- phase A-consume: derive + stage quartets ----
#pragma unroll
    for (int k = 0; k < 3; k++) {
        if (act[k]) {
            float pme, pve, pmo, pvo;
            if (okv[k]) {
                pme = Ld[k].x * Lcd[k].x;            // IEEE f32, matches np
                pve = Lcd[k].x / (Ld[k].x + EPSF);   // IEEE f32 div (argmax-critical)
                pmo = Ld[k].y * Lcd[k].y;
                pvo = Lcd[k].y / (Ld[k].y + EPSF);
            } else {
                pme = -INFINITY; pve = -INFINITY; pmo = -INFINITY; pvo = -INFINITY;
            }
            const int r = rr_[k], j = jj_[k];
            st_e[r][j] = make_float4(pme, pve, Lcs[k].x, Lcs[k].x * Ls[k].x);
            st_o[r][j] = make_float4(pmo, pvo, Lcs[k].y, Lcs[k].y * Ls[k].y);
        }
    }
    __syncthreads();
    if (t == 0) {
        float acc = 0.f;
#pragma unroll
        for (int i = 0; i < 12; i++) acc += red[i];
        scal[0] = acc;
        scal[1] = 1.f / (1.f + expf(-wsfdg[0]));
    }
    __syncthreads();

    // ---- phase B: one output px per thread ----
    const int oyl = t / 96;          // 0..7
    const int ox  = t - oyl * 96;    // 0..95
    const int r0  = oyl * 2;

    float bm = -INFINITY, bv = -INFINITY;
    float pvm = 0.f, pmn = 0.f;      // companions: pv@argmax(pm), pm@argmax(pv)
    float nom = 0.f, den = 0.f;

#pragma unroll
    for (int dy = 0; dy < 5; dy++) {
        const int r = r0 + dy;
        const float w0 = sw_row[dy * 5 + 0];
        const float w1 = sw_row[dy * 5 + 1];
        const float w2 = sw_row[dy * 5 + 2];
        const float w3 = sw_row[dy * 5 + 3];
        const float w4 = sw_row[dy * 5 + 4];

        const float4 E0 = st_e[r][ox];       // dx=0
        const float4 O0 = st_o[r][ox];       // dx=1
        const float4 E1 = st_e[r][ox + 1];   // dx=2
        const float4 O1 = st_o[r][ox + 1];   // dx=3
        const float4 E2 = st_e[r][ox + 2];   // dx=4

        // taps in exact j order: dx = 0,1,2,3,4; strict > = first-max wins
        if (E0.x > bm) { bm = E0.x; pvm = E0.y; }
        if (E0.y > bv) { bv = E0.y; pmn = E0.x; }
        if (O0.x > bm) { bm = O0.x; pvm = O0.y; }
        if (O0.y > bv) { bv = O0.y; pmn = O0.x; }
        if (E1.x > bm) { bm = E1.x; pvm = E1.y; }
        if (E1.y > bv) { bv = E1.y; pmn = E1.x; }
        if (O1.x > bm) { bm = O1.x; pvm = O1.y; }
        if (O1.y > bv) { bv = O1.y; pmn = O1.x; }
        if (E2.x > bm) { bm = E2.x; pvm = E2.y; }
        if (E2.y > bv) { bv = E2.y; pmn = E2.x; }

        nom += w0 * E0.w; den += w0 * E0.z;
        nom += w1 * O0.w; den += w1 * O0.z;
        nom += w2 * E1.w; den += w2 * E1.z;
        nom += w3 * O1.w; den += w3 * O1.z;
        nom += w4 * E2.w; den += w4 * E2.z;
    }

    // recover winner values algebraically (post-argmax: fast 1-ulp ops safe)
    //   bm = d_M*cd_M, pvm = cd_M/d_M ; bv = cd_N/d_N, pmn = d_N*cd_N
    const float t1 = pmn * pvm;
    const float t2 = bv * bm;
    const float mdm = fabsf(fsqrt(t1 * frcp(t2)));
    const float cfd = fsqrt(t1 * t2);

    const float sumsw = scal[0];
    const float wsfd  = scal[1];
    const float sfd  = (1.f - wsfd) * mdm + wsfd * mdm * mdm;
    const float ssp  = nom * frcp(den + EPSF);
    const float cssp = den * frcp(sumsw + EPSF);

    const int opx = (8 * bx + oyl) * NWO + ox;
    const size_t oidx = ((size_t)(b * NC) + c) * NPX + opx;
    ws4[oidx] = make_float4(cssp * ssp, cssp, sfd, cfd);   // {A,B,S,C}
}

// =====================================================================
// k2: channel mix + final combine. Thread = (o, 4-px quad); float4 LDS
// reads (pad 36 keeps rows 16B-aligned) + dwordx4 stores.
// =====================================================================
#define K2PX 32
#define K2PAD 36

__global__ __launch_bounds__(256, 8) void k2(
    const float4* __restrict__ ws4,
    const float* __restrict__ wpropg,
    const float* __restrict__ chwg,
    const float* __restrict__ biasg,
    float* __restrict__ out)
{
    __shared__ float cw_s[NC * NC];
    __shared__ float wp_s[NC];
    __shared__ float bias_s[NC];
    __shared__ float A_s[NC][K2PAD];
    __shared__ float B_s[NC][K2PAD];
    __shared__ float S_s[NC][K2PAD];
    __shared__ float C_s[NC][K2PAD];
    __shared__ float red[4];
    __shared__ float scal[1];

    const int t   = threadIdx.x;
    const int b   = blockIdx.y;
    const int px0 = blockIdx.x * K2PX;
    const int q   = t & 7;               // px quad 0..7 (4 px each)
    const int o   = t >> 3;              // 0..31

    float part = 0.f;
    for (int i = t; i < NC * NC; i += 256) {
        float v = softplusf(chwg[i]); cw_s[i] = v; part += v;
    }
    if (t < NC) { wp_s[t] = softplusf(wpropg[t]); bias_s[t] = biasg[t]; }
#pragma unroll
    for (int m = 32; m >= 1; m >>= 1) part += __shfl_xor(part, m, 64);
    if ((t & 63) == 0) red[t >> 6] = part;

    // stage quartets for this px tile (32 i x 32 px)
    const size_t bb = (size_t)b * NC * NPX;
#pragma unroll
    for (int idx = 0; idx < NC * K2PX; idx += 256) {
        const int i  = (idx + t) >> 5;
        const int pp = (idx + t) & (K2PX - 1);
        const float4 qv = ws4[bb + (size_t)i * NPX + px0 + pp];
        A_s[i][pp] = qv.x;
        B_s[i][pp] = qv.y;
        S_s[i][pp] = qv.z;
        C_s[i][pp] = qv.w;
    }
    __syncthreads();
    if (t == 0) scal[0] = red[0] + red[1] + red[2] + red[3];
    __syncthreads();

    const float sumcw = scal[0];

    float4 nom4 = make_float4(0.f, 0.f, 0.f, 0.f);
    float4 den4 = make_float4(0.f, 0.f, 0.f, 0.f);
#pragma unroll
    for (int i = 0; i < NC; i++) {
        const float4 a4 = *(const float4*)&A_s[i][4 * q];
        const float4 b4 = *(const float4*)&B_s[i][4 * q];
        const float w = cw_s[o * NC + i];
        nom4.x += w * a4.x; nom4.y += w * a4.y; nom4.z += w * a4.z; nom4.w += w * a4.w;
        den4.x += w * b4.x; den4.y += w * b4.y; den4.z += w * b4.z; den4.w += w * b4.w;
    }

    const float4 sfd4 = *(const float4*)&S_s[o][4 * q];
    const float4 cfd4 = *(const float4*)&C_s[o][4 * q];
    const float wp   = wp_s[o];
    const float bias = bias_s[o];
    const float csn  = frcp(sumcw + EPSF);

    float so[4], co[4];
#pragma unroll
    for (int k = 0; k < 4; k++) {
        const float nm  = (k == 0) ? nom4.x : (k == 1) ? nom4.y : (k == 2) ? nom4.z : nom4.w;
        const float dn  = (k == 0) ? den4.x : (k == 1) ? den4.y : (k == 2) ? den4.z : den4.w;
        const float sfd = (k == 0) ? sfd4.x : (k == 1) ? sfd4.y : (k == 2) ? sfd4.z : sfd4.w;
        const float cfd = (k == 0) ? cfd4.x : (k == 1) ? cfd4.y : (k == 2) ? cfd4.z : cfd4.w;

        const float smix  = nm * frcp(dn + EPSF);
        const float csmix = dn * csn;
        const float a = wp * csmix;

        float sout = (a * smix + cfd * sfd) * frcp(a + cfd + EPSF);
        const float csout = (a + cfd) * frcp(wp + 1.f);

        sout += bias;
        sout = frcp(1.f + __expf(-(sout * 2.f - 1.f))) * 0.5f + 0.5f;

        so[k] = sout;
        co[k] = csout * 0.25f;
    }

    const size_t oidx = bb + (size_t)o * NPX + px0 + 4 * q;
    *(float4*)&out[oidx]                     = make_float4(so[0], so[1], so[2], so[3]);
    *(float4*)&out[(size_t)NPLANE + oidx]    = make_float4(co[0], co[1], co[2], co[3]);
}

// =====================================================================
// Fallback: round-4 fused kernel (used if ws_size is too small)
// =====================================================================
#define TW    8
#define TH    4
#define TPP   33

__global__ __launch_bounds__(256, 4) void fused_kernel(
    const float* __restrict__ dg,
    const float* __restrict__ cdg,
    const float* __restrict__ sg,
    const float* __restrict__ csg,
    const float* __restrict__ wsfdg,
    const float* __restrict__ wpropg,
    const float* __restrict__ spwg,
    const float* __restrict__ chwg,
    const float* __restrict__ biasg,
    float* __restrict__ out)
{
    __shared__ float sw_s[NC * 25];
    __shared__ float cw_s[NC * NC];
    __shared__ float wp_s[NC];
    __shared__ float bias_s[NC];
    __shared__ float A_s[NC][TPP];
    __shared__ float B_s[NC][TPP];
    __shared__ float S_s[NC][TPP];
    __shared__ float C_s[NC][TPP];
    __shared__ float red[8];
    __shared__ float scal[3];

    const int t = threadIdx.x;
    const int b = blockIdx.z;
    const int tile_x = blockIdx.x * TW;
    const int tile_y = blockIdx.y * TH;

    float p_sw = 0.f, p_cw = 0.f;
    for (int i = t; i < NC * 25; i += 256) { float v = softplusf(spwg[i]); sw_s[i] = v; p_sw += v; }
    for (int i = t; i < NC * NC; i += 256) { float v = softplusf(chwg[i]); cw_s[i] = v; p_cw += v; }
    if (t < NC) { wp_s[t] = softplusf(wpropg[t]); bias_s[t] = biasg[t]; }
#pragma unroll
    for (int m = 32; m >= 1; m >>= 1) {
        p_sw += __shfl_xor(p_sw, m, 64);
        p_cw += __shfl_xor(p_cw, m, 64);
    }
    if ((t & 63) == 0) { red[(t >> 6) * 2] = p_sw; red[(t >> 6) * 2 + 1] = p_cw; }
    __syncthreads();
    if (t == 0) {
        scal[0] = red[0] + red[2] + red[4] + red[6];
        scal[1] = red[1] + red[3] + red[5] + red[7];
        scal[2] = 1.f / (1.f + expf(-wsfdg[0]));
    }
    __syncthreads();

    const float sumsw = scal[0];
    const float sumcw = scal[1];
    const float wsfd  = scal[2];

    const int c  = t >> 3;
    const int tr = (t >> 2) & 1;
    const int q  = t & 3;
    const int oy0 = tile_y + tr * 2;
    const int ox0 = tile_x + q * 2;
    const int cb = ox0 * 2 - 2;
    const int rb = oy0 * 2 - 2;
    const size_t base = ((size_t)(b * NC) + c) * NH * NW;
    const float* __restrict__ dp  = dg  + base;
    const float* __restrict__ cdp = cdg + base;
    const float* __restrict__ sp  = sg  + base;
    const float* __restrict__ csp = csg + base;

    bool slotok[4];
#pragma unroll
    for (int k = 0; k < 4; k++) slotok[k] = (cb + 2 * k >= 0) && (cb + 2 * k + 1 < NW);
    bool ciok[7];
#pragma unroll
    for (int ci = 0; ci < 7; ci++) ciok[ci] = ((unsigned)(cb + ci) < NW);

    float bm[2][2], dM[2][2], cM[2][2];
    float bn[2][2], dN[2][2], cN[2][2];
    float nom[2][2], den[2][2];
#pragma unroll
    for (int r = 0; r < 2; r++)
#pragma unroll
        for (int q2 = 0; q2 < 2; q2++) {
            bm[r][q2] = -INFINITY; bn[r][q2] = -INFINITY;
            dM[r][q2] = 0.f; cM[r][q2] = 0.f; dN[r][q2] = 0.f; cN[r][q2] = 0.f;
            nom[r][q2] = 0.f; den[r][q2] = 0.f;
        }

#pragma unroll
    for (int rr = 0; rr < 7; rr++) {
        const int iy = rb + rr;
        if ((unsigned)iy < NH) {
            const int roff = iy * NW + cb;
            float dv[8], cdv[8], sv[8], csv[8];
#pragma unroll
            for (int k = 0; k < 4; k++) {
                float2 vD, vCD, vS, vCS;
                if (slotok[k]) {
                    vD  = *(const float2*)(dp  + roff + 2 * k);
                    vCD = *(const float2*)(cdp + roff + 2 * k);
                    vS  = *(const float2*)(sp  + roff + 2 * k);
                    vCS = *(const float2*)(csp + roff + 2 * k);
                } else {
                    vD = make_float2(0.f, 0.f); vCD = vD; vS = vD; vCS = vD;
                }
                dv[2*k] = vD.x;  dv[2*k+1] = vD.y;
                cdv[2*k] = vCD.x; cdv[2*k+1] = vCD.y;
                sv[2*k] = vS.x;  sv[2*k+1] = vS.y;
                csv[2*k] = vCS.x; csv[2*k+1] = vCS.y;
            }
            float pm[7], pv[7];
#pragma unroll
            for (int ci = 0; ci < 7; ci++) {
                pm[ci] = dv[ci] * cdv[ci];
                pv[ci] = cdv[ci] / (dv[ci] + EPSF);
            }
#pragma unroll
            for (int r = 0; r < 2; r++) {
                const int dy = rr - 2 * r;
                if (dy >= 0 && dy <= 4) {
#pragma unroll
                    for (int dx = 0; dx < 5; dx++) {
                        const float w = sw_s[c * 25 + dy * 5 + dx];
#pragma unroll
                        for (int q2 = 0; q2 < 2; q2++) {
                            const int ci = 2 * q2 + dx;
                            if (ciok[ci]) {
                                if (pm[ci] > bm[r][q2]) { bm[r][q2] = pm[ci]; dM[r][q2] = dv[ci]; cM[r][q2] = cdv[ci]; }
                                if (pv[ci] > bn[r][q2]) { bn[r][q2] = pv[ci]; dN[r][q2] = dv[ci]; cN[r][q2] = cdv[ci]; }
                                nom[r][q2] += w * (csv[ci] * sv[ci]);
                                den[r][q2] += w * csv[ci];
                            }
                        }
                    }
                }
            }
        }
    }

#pragma unroll
    for (int r = 0; r < 2; r++)
#pragma unroll
        for (int q2 = 0; q2 < 2; q2++) {
            const float mdm  = fabsf(dN[r][q2] / (dM[r][q2] + EPSF));
            const float sfd  = (1.f - wsfd) * mdm + wsfd * mdm * mdm;
            const float cfd  = cM[r][q2] * cN[r][q2];
            const float ssp  = nom[r][q2] / (den[r][q2] + EPSF);
            const float cssp = den[r][q2] / (sumsw + EPSF);
            const int p = (tr * 2 + r) * TW + (q * 2 + q2);
            A_s[c][p] = cssp * ssp;
            B_s[c][p] = cssp;
            S_s[c][p] = sfd;
            C_s[c][p] = cfd;
        }
    __syncthreads();

    const int p  = t & 31;
    const int o0 = t >> 5;
    const int py = p >> 3;
    const int pxx = p & 7;
    const int opx = (tile_y + py) * NWO + tile_x + pxx;

    float nom2[4], den2[4];
#pragma unroll
    for (int k = 0; k < 4; k++) { nom2[k] = 0.f; den2[k] = 0.f; }

#pragma unroll
    for (int i = 0; i < NC; i++) {
        const float a  = A_s[i][p];
        const float b2 = B_s[i][p];
#pragma unroll
        for (int k = 0; k < 4; k++) {
            const float w = cw_s[(o0 + 8 * k) * NC + i];
            nom2[k] += w * a;
            den2[k] += w * b2;
        }
    }

#pragma unroll
    for (int k = 0; k < 4; k++) {
        const int o = o0 + 8 * k;
        const float smix  = nom2[k] / (den2[k] + EPSF);
        const float csmix = den2[k] / (sumcw + EPSF);
        const float wp    = wp_s[o];
        const float sfd   = S_s[o][p];
        const float cfd   = C_s[o][p];

        float sout = (wp * csmix * smix + cfd * sfd) / (wp * csmix + cfd + EPSF);
        const float csout = (wp * csmix + cfd) / (wp + 1.f);

        sout += bias_s[o];
        sout = 1.f / (1.f + expf(-(sout * 2.f - 1.f))) * 0.5f + 0.5f;

        const int oidx = ((b * NC) + o) * NPX + opx;
        out[oidx]          = sout;
        out[NPLANE + oidx] = csout * 0.25f;
    }
}

extern "C" void kernel_launch(void* const* d_in, const int* in_sizes, int n_in,
                              void* d_out, int out_size, void* d_ws, size_t ws_size,
                              hipStream_t stream) {
    const float* d     = (const float*)d_in[0];
    const float* cd    = (const float*)d_in[1];
    const float* s     = (const float*)d_in[2];
    const float* cs    = (const float*)d_in[3];
    const float* wsfd  = (const float*)d_in[4];
    const float* wprop = (const float*)d_in[5];
    const float* spw   = (const float*)d_in[6];
    const float* chw   = (const float*)d_in[7];
    const float* bias  = (const float*)d_in[8];
    float* out = (float*)d_out;

    const size_t need = (size_t)4 * NPLANE * sizeof(float);   // 18.9 MB
    if (ws_size >= need) {
        float4* ws4 = (float4*)d_ws;
        k1<<<dim3(NHO / 8, NC, NB), K1T, 0, stream>>>(d, cd, s, cs, wsfd, spw, ws4);
        k2<<<dim3(NPX / K2PX, NB), 256, 0, stream>>>(ws4, wprop, chw, bias, out);
    } else {
        fused_kernel<<<dim3(NWO / TW, NHO / TH, NB), 256, 0, stream>>>(
            d, cd, s, cs, wsfd, wprop, spw, chw, bias, out);
    }
}